// Round 1
// baseline (107.005 us; speedup 1.0000x reference)
//
#include <hip/hip_runtime.h>
#include <stdint.h>

typedef __attribute__((ext_vector_type(8))) short short8;
typedef __attribute__((ext_vector_type(4))) float f32x4;

#define L_Q 8192
#define N_KV 8192
#define D_K 128
#define NKV_VALID 8064  /* N - PAD; multiple of 32 */

// ---------- helpers ----------
__device__ __forceinline__ unsigned short f2bf(float x) {
  unsigned int u = __float_as_uint(x);
  u += 0x7FFFu + ((u >> 16) & 1u);           // round-to-nearest-even
  return (unsigned short)(u >> 16);
}
__device__ __forceinline__ unsigned int pk2(float lo, float hi) {
  return (unsigned int)f2bf(lo) | ((unsigned int)f2bf(hi) << 16);
}
__device__ __forceinline__ void gload16(const void* g, void* l) {
  __builtin_amdgcn_global_load_lds(
      (const __attribute__((address_space(1))) unsigned int*)g,
      (__attribute__((address_space(3))) unsigned int*)l, 16, 0, 0);
}

// ---------- prep: fp32 -> bf16 cast (optionally scaled) ----------
__global__ void cast_kernel(const float* __restrict__ src,
                            unsigned short* __restrict__ dst,
                            int n8, float scale) {
  int i = blockIdx.x * 256 + threadIdx.x;
  if (i >= n8) return;
  const float4* s = (const float4*)src;
  float4 a = s[2 * i], b = s[2 * i + 1];
  uint4 o;
  o.x = pk2(a.x * scale, a.y * scale);
  o.y = pk2(a.z * scale, a.w * scale);
  o.z = pk2(b.x * scale, b.y * scale);
  o.w = pk2(b.z * scale, b.w * scale);
  *(uint4*)(dst + (size_t)i * 8) = o;
}

// ---------- prep: V [8192][128] fp32 -> Vt [128][8192] bf16 ----------
__global__ void transpose_v_kernel(const float* __restrict__ V,
                                   unsigned short* __restrict__ Vt) {
  __shared__ unsigned short tile[64][65];
  const int bkv = blockIdx.x >> 1;  // 0..127
  const int bdk = blockIdx.x & 1;   // 0..1
  const int kv0 = bkv << 6, dk0 = bdk << 6;
  const int tid = threadIdx.x;
  const int r = tid >> 2;           // 0..63
  const int c0 = (tid & 3) << 4;    // 0,16,32,48
#pragma unroll
  for (int j = 0; j < 4; ++j) {
    float4 v = *(const float4*)(V + (size_t)(kv0 + r) * D_K + dk0 + c0 + 4 * j);
    tile[r][c0 + 4 * j + 0] = f2bf(v.x);
    tile[r][c0 + 4 * j + 1] = f2bf(v.y);
    tile[r][c0 + 4 * j + 2] = f2bf(v.z);
    tile[r][c0 + 4 * j + 3] = f2bf(v.w);
  }
  __syncthreads();
  __align__(16) unsigned short tmp[16];
#pragma unroll
  for (int j = 0; j < 16; ++j) tmp[j] = tile[c0 + j][r];
  unsigned short* o = Vt + (size_t)(dk0 + r) * N_KV + kv0 + c0;
  *(uint4*)(o) = *(uint4*)(tmp);
  *(uint4*)(o + 8) = *(uint4*)(tmp + 8);
}

// ---------- main: flash attention with kv-split partials ----------
// Qb pre-scaled by (1/sqrt(dk))*log2(e): softmax runs in exp2 domain.
// Swapped QK^T: st = mfma(Kfrag, Qfrag) -> S^T[kv][q]; per-lane q = lane&15.
__global__ __launch_bounds__(256) void attn_kernel(
    const unsigned short* __restrict__ Qb,   // [8192][128] bf16 (pre-scaled)
    const unsigned short* __restrict__ Kb,   // [8192][128] bf16
    const unsigned short* __restrict__ Vtb,  // [128][8192] bf16
    float* __restrict__ Opart,               // [nslot][64][128] or null
    float2* __restrict__ MLpart,             // [nslot][64] or null
    float* __restrict__ Out,                 // used when nsplit==1
    int nsplit) {
  const int bid = blockIdx.x;
  const int t = 127 - bid / nsplit;       // longest tiles dispatched first
  const int s = bid % nsplit;
  const int q0 = t << 6;
  const int kv_len = min(q0 + 64, NKV_VALID);
  const int n = kv_len >> 5;              // 32-wide kv units
  const int u0 = (s * n) / nsplit;
  const int u1 = ((s + 1) * n) / nsplit;
  const int slot = t * nsplit + s;
  const int tid = threadIdx.x;
  const int lane = tid & 63;
  const int w = tid >> 6;                 // wave 0..3
  const int c = lane & 15;                // q col within 16
  const int g = lane >> 4;                // k-group 0..3
  const int qw = q0 + (w << 4);           // wave's first q row

  if (u0 == u1) {                         // empty split: record and leave
    if (MLpart && lane < 16)
      MLpart[slot * 64 + (w << 4) + lane] = make_float2(-3e38f, 0.f);
    return;
  }

  __shared__ __align__(16) char lds[20480];
  char* const Klds = lds;                 // [32 kv][256B], XOR (row&7)<<4
  char* const Vlds = lds + 8192;          // [128 dk][64B], XOR (row&3)<<4
  char* const Plds = lds + 16384 + (w << 10);  // per-wave [16 q][64B]

  // Q fragments (B-operand), 4 k-chunks of 32
  short8 qf[4];
  {
    const char* qrow = (const char*)(Qb + (size_t)(qw + c) * D_K);
#pragma unroll
    for (int kc = 0; kc < 4; ++kc)
      qf[kc] = *(const short8*)(qrow + kc * 64 + g * 16);
  }

  f32x4 acc[8] = {};                      // O[16 q][128 dk]: row=4g+r, col=16d+c
  float m2 = -3e38f, lsum = 0.f;
  const int swp = (c & 3) << 4;           // swizzle for P / Vt reads (row%4 == c%4)

  for (int u = u0; u < u1; ++u) {
    const int kv0 = u << 5;
    __syncthreads();                      // previous tile fully consumed
    // ---- stage K(8KB) + Vt(8KB) via global_load_lds, pre-swizzled source ----
#pragma unroll
    for (int ii = 0; ii < 2; ++ii) {
      const int ck = 2 * w + ii;          // this wave's chunks
      {
        const int row = (ck << 2) + (lane >> 4);
        const int colb = (lane & 15) << 4;
        const size_t srcb = (size_t)(kv0 + row) * 256 + (size_t)(colb ^ ((row & 7) << 4));
        gload16((const char*)Kb + srcb, Klds + (ck << 10));
      }
      {
        const int row = (ck << 4) + (lane >> 2);
        const int colb = (lane & 3) << 4;
        const size_t srcb = (size_t)row * 16384 + (size_t)kv0 * 2 + (size_t)(colb ^ ((row & 3) << 4));
        gload16((const char*)Vtb + srcb, Vlds + (ck << 10));
      }
    }
    __syncthreads();                      // vmcnt(0) drained by compiler
    if (kv0 > qw + 15) continue;          // whole unit above diagonal for this wave

    // ---- QK^T (swapped): S^T[kv][q] ----
    f32x4 st[2] = {};
#pragma unroll
    for (int tt = 0; tt < 2; ++tt) {
      const int krow = (tt << 4) + c;
      const char* kbase = Klds + krow * 256;
      const int swk = (krow & 7) << 4;
#pragma unroll
      for (int kc = 0; kc < 4; ++kc) {
        short8 kf = *(const short8*)(kbase + ((kc * 64 + g * 16) ^ swk));
        st[tt] = __builtin_amdgcn_mfma_f32_16x16x32_bf16(kf, qf[kc], st[tt], 0, 0, 0);
      }
    }
    // ---- causal mask (kv > q -> -inf) ----
#pragma unroll
    for (int tt = 0; tt < 2; ++tt) {
      if (kv0 + (tt << 4) + 15 > qw) {
        const int kvb = kv0 + (tt << 4) + (g << 2);
#pragma unroll
        for (int r = 0; r < 4; ++r)
          if (kvb + r > qw + c) st[tt][r] = -__builtin_inff();
      }
    }
    // ---- online softmax (exp2 domain), per-lane row q=c ----
    float mx = fmaxf(fmaxf(fmaxf(st[0][0], st[0][1]), fmaxf(st[0][2], st[0][3])),
                     fmaxf(fmaxf(st[1][0], st[1][1]), fmaxf(st[1][2], st[1][3])));
    mx = fmaxf(mx, __shfl_xor(mx, 16));
    mx = fmaxf(mx, __shfl_xor(mx, 32));
    const float m2new = fmaxf(m2, mx);
    const float alpha = exp2f(m2 - m2new);
    float p[8], psum = 0.f;
#pragma unroll
    for (int tt = 0; tt < 2; ++tt)
#pragma unroll
      for (int r = 0; r < 4; ++r) {
        const float v = exp2f(st[tt][r] - m2new);
        p[(tt << 2) + r] = v;
        psum += v;
      }
    psum += __shfl_xor(psum, 16);
    psum += __shfl_xor(psum, 32);
    lsum = lsum * alpha + psum;
    m2 = m2new;
    // rescale O (rows 4g+r need alpha of q=4g+r)
#pragma unroll
    for (int r = 0; r < 4; ++r) {
      const float fr = __shfl(alpha, (g << 2) + r);
#pragma unroll
      for (int d = 0; d < 8; ++d) acc[d][r] *= fr;
    }
    // ---- P -> bf16 into per-wave LDS [16 q][32 kv], swizzled ----
    {
      char* prow = Plds + c * 64;
#pragma unroll
      for (int tt = 0; tt < 2; ++tt)
#pragma unroll
        for (int uu = 0; uu < 2; ++uu) {
          *(unsigned int*)(prow + ((((tt << 5) + (g << 3) + (uu << 2))) ^ swp)) =
              pk2(p[(tt << 2) + (uu << 1)], p[(tt << 2) + (uu << 1) + 1]);
        }
    }
    // ---- PV: O += P[16x32] x V[32x128] ----
    {
      const short8 pa = *(const short8*)(Plds + c * 64 + ((g << 4) ^ swp));
#pragma unroll
      for (int d = 0; d < 8; ++d) {
        const short8 vb = *(const short8*)(Vlds + (d << 10) + c * 64 + ((g << 4) ^ swp));
        acc[d] = __builtin_amdgcn_mfma_f32_16x16x32_bf16(pa, vb, acc[d], 0, 0, 0);
      }
    }
  }

  // ---- epilogue ----
  if (Opart) {
    float* op = Opart + (size_t)slot * 8192 + (size_t)(w << 4) * 128;
#pragma unroll
    for (int d = 0; d < 8; ++d)
#pragma unroll
      for (int r = 0; r < 4; ++r)
        op[((g << 2) + r) * 128 + (d << 4) + c] = acc[d][r];
    if (lane < 16)
      MLpart[slot * 64 + (w << 4) + lane] = make_float2(m2, lsum);
  } else {
#pragma unroll
    for (int r = 0; r < 4; ++r) {
      const float lr = __shfl(lsum, (g << 2) + r);
      const float inv = 1.0f / lr;
#pragma unroll
      for (int d = 0; d < 8; ++d)
        Out[(size_t)(qw + (g << 2) + r) * 128 + (d << 4) + c] = acc[d][r] * inv;
    }
  }
}

// ---------- combine 4 kv-split partials ----------
__global__ void combine_kernel(const float* __restrict__ Opart,
                               const float2* __restrict__ MLpart,
                               float* __restrict__ Out) {
  const int gidx = blockIdx.x * 256 + threadIdx.x;  // 8192*32 threads
  const int q = gidx >> 5;
  const int cb = (gidx & 31) << 2;
  const int t = q >> 6, rl = q & 63;
  float m[4], lv[4], M = -3e38f;
#pragma unroll
  for (int s = 0; s < 4; ++s) {
    float2 ml = MLpart[(t * 4 + s) * 64 + rl];
    m[s] = ml.x; lv[s] = ml.y;
    M = fmaxf(M, m[s]);
  }
  float nx = 0, ny = 0, nz = 0, nw = 0, den = 0;
#pragma unroll
  for (int s = 0; s < 4; ++s) {
    if (m[s] > -1e37f) {
      const float wgt = exp2f(m[s] - M);
      den += lv[s] * wgt;
      const float4 o = *(const float4*)(Opart + (size_t)(t * 4 + s) * 8192 + rl * 128 + cb);
      nx += wgt * o.x; ny += wgt * o.y; nz += wgt * o.z; nw += wgt * o.w;
    }
  }
  const float inv = 1.f / den;
  float4 r; r.x = nx * inv; r.y = ny * inv; r.z = nz * inv; r.w = nw * inv;
  *(float4*)(Out + (size_t)q * 128 + cb) = r;
}

extern "C" void kernel_launch(void* const* d_in, const int* in_sizes, int n_in,
                              void* d_out, int out_size, void* d_ws, size_t ws_size,
                              hipStream_t stream) {
  (void)in_sizes; (void)n_in; (void)out_size;
  const float* Q = (const float*)d_in[0];
  const float* K = (const float*)d_in[1];
  const float* V = (const float*)d_in[2];
  float* out = (float*)d_out;
  char* ws = (char*)d_ws;

  unsigned short* Qb  = (unsigned short*)(ws);
  unsigned short* Kb  = (unsigned short*)(ws + (1u << 21));
  unsigned short* Vtb = (unsigned short*)(ws + (2u << 21));
  float2* MLp = (float2*)(ws + (3u << 21));
  float*  Op  = (float*)(ws + (3u << 21) + (1u << 18));
  const size_t needed = (size_t)(3u << 21) + (1u << 18) + (size_t)512 * 64 * 128 * 4;
  const int nsplit = (ws_size >= needed) ? 4 : 1;

  const float qscale = 0.12751742941349835f;  // (1/sqrt(128)) * log2(e)
  cast_kernel<<<512, 256, 0, stream>>>(Q, Qb, 131072, qscale);
  cast_kernel<<<512, 256, 0, stream>>>(K, Kb, 131072, 1.0f);
  transpose_v_kernel<<<256, 256, 0, stream>>>(V, Vtb);
  if (nsplit == 4) {
    attn_kernel<<<512, 256, 0, stream>>>(Qb, Kb, Vtb, Op, MLp, nullptr, 4);
    combine_kernel<<<1024, 256, 0, stream>>>(Op, MLp, out);
  } else {
    attn_kernel<<<128, 256, 0, stream>>>(Qb, Kb, Vtb, nullptr, nullptr, out, 1);
  }
}

// Round 2
// 97.061 us; speedup vs baseline: 1.1025x; 1.1025x over previous
//
#include <hip/hip_runtime.h>
#include <stdint.h>

typedef __attribute__((ext_vector_type(8))) short short8;
typedef __attribute__((ext_vector_type(4))) float f32x4;

#define D_K 128
#define N_KV 8192
#define NKV_VALID 8064  /* N - PAD; 252 units of 32 */
#define NT 128          /* 64-row q tiles */

// ---------- helpers ----------
__device__ __forceinline__ unsigned short f2bf(float x) {
  unsigned int u = __float_as_uint(x);
  u += 0x7FFFu + ((u >> 16) & 1u);  // RNE
  return (unsigned short)(u >> 16);
}
__device__ __forceinline__ unsigned int pk2(float lo, float hi) {
  return (unsigned int)f2bf(lo) | ((unsigned int)f2bf(hi) << 16);
}
__device__ __forceinline__ void gload16(const void* g, void* l) {
  __builtin_amdgcn_global_load_lds(
      (const __attribute__((address_space(1))) unsigned int*)g,
      (__attribute__((address_space(3))) unsigned int*)l, 16, 0, 0);
}
__device__ __host__ __forceinline__ int nunits(int t) {
  int n = 2 * t + 2;
  return n > 252 ? 252 : n;
}

// ---------- prep: fp32 -> bf16 cast (optionally scaled) ----------
__global__ void cast_kernel(const float* __restrict__ src,
                            unsigned short* __restrict__ dst,
                            int n8, float scale) {
  int i = blockIdx.x * 256 + threadIdx.x;
  if (i >= n8) return;
  const float4* s = (const float4*)src;
  float4 a = s[2 * i], b = s[2 * i + 1];
  uint4 o;
  o.x = pk2(a.x * scale, a.y * scale);
  o.y = pk2(a.z * scale, a.w * scale);
  o.z = pk2(b.x * scale, b.y * scale);
  o.w = pk2(b.z * scale, b.w * scale);
  *(uint4*)(dst + (size_t)i * 8) = o;
}

// ---------- prep: V [8192][128] fp32 -> Vt [128][8192] bf16 ----------
__global__ void transpose_v_kernel(const float* __restrict__ V,
                                   unsigned short* __restrict__ Vt) {
  __shared__ unsigned short tile[64][65];
  const int bkv = blockIdx.x >> 1;
  const int bdk = blockIdx.x & 1;
  const int kv0 = bkv << 6, dk0 = bdk << 6;
  const int tid = threadIdx.x;
  const int r = tid >> 2;
  const int c0 = (tid & 3) << 4;
#pragma unroll
  for (int j = 0; j < 4; ++j) {
    float4 v = *(const float4*)(V + (size_t)(kv0 + r) * D_K + dk0 + c0 + 4 * j);
    tile[r][c0 + 4 * j + 0] = f2bf(v.x);
    tile[r][c0 + 4 * j + 1] = f2bf(v.y);
    tile[r][c0 + 4 * j + 2] = f2bf(v.z);
    tile[r][c0 + 4 * j + 3] = f2bf(v.w);
  }
  __syncthreads();
  __align__(16) unsigned short tmp[16];
#pragma unroll
  for (int j = 0; j < 16; ++j) tmp[j] = tile[c0 + j][r];
  unsigned short* o = Vt + (size_t)(dk0 + r) * N_KV + kv0 + c0;
  *(uint4*)(o) = *(uint4*)(tmp);
  *(uint4*)(o + 8) = *(uint4*)(tmp + 8);
}

// ---------- main: balanced-chunk flash attention, double-buffered ----------
__global__ __launch_bounds__(256, 4) void attn_kernel(
    const unsigned short* __restrict__ Qb,   // [8192][128] bf16 pre-scaled
    const unsigned short* __restrict__ Kb,   // [8192][128] bf16
    const unsigned short* __restrict__ Vtb,  // [128][8192] bf16
    float* __restrict__ Opart,               // [slots][64][128]
    float2* __restrict__ MLpart,             // [slots][64]
    int U) {
  // ---- block -> (tile t, chunk s); big tiles dispatched first ----
  int rem = blockIdx.x, t = NT - 1;
  for (;; --t) {
    int nb = (nunits(t) + U - 1) / U;
    if (rem < nb) break;
    rem -= nb;
  }
  const int s = rem;
  const int q0 = t << 6;
  const int n = nunits(t);
  const int u0 = s * U;
  const int u1 = min(u0 + U, n);
  const int slot = blockIdx.x;
  const int tid = threadIdx.x;
  const int lane = tid & 63;
  const int w = tid >> 6;
  const int c = lane & 15;
  const int g = lane >> 4;
  const int qw = q0 + (w << 4);

  // 2 x (K 8KB + Vt 8KB) double buffer + 4 x 1KB per-wave P
  __shared__ __align__(16) char lds[36864];

  short8 qf[4];
  {
    const char* qrow = (const char*)(Qb + (size_t)(qw + c) * D_K);
#pragma unroll
    for (int kc = 0; kc < 4; ++kc)
      qf[kc] = *(const short8*)(qrow + kc * 64 + g * 16);
  }

  f32x4 acc[8] = {};
  float m2 = -3e38f, lsum = 0.f;
  const int swp = (c & 3) << 4;

  auto stage = [&](int u, int b) {
    const int kv0s = u << 5;
    char* Kl = lds + b * 16384;
    char* Vl = Kl + 8192;
#pragma unroll
    for (int ii = 0; ii < 2; ++ii) {
      const int ck = 2 * w + ii;
      {
        const int row = (ck << 2) + (lane >> 4);
        const int colb = (lane & 15) << 4;
        gload16((const char*)Kb + (size_t)(kv0s + row) * 256 + (size_t)(colb ^ ((row & 7) << 4)),
                Kl + (ck << 10));
      }
      {
        const int row = (ck << 4) + (lane >> 2);
        const int colb = (lane & 3) << 4;
        gload16((const char*)Vtb + (size_t)row * 16384 + (size_t)kv0s * 2 + (size_t)(colb ^ ((row & 3) << 4)),
                Vl + (ck << 10));
      }
    }
  };

  stage(u0, 0);
  for (int u = u0; u < u1; ++u) {
    const int kv0 = u << 5;
    const int cb = (u - u0) & 1;
    char* const Kl = lds + cb * 16384;
    char* const Vl = Kl + 8192;
    char* const Pl = lds + 32768 + (w << 10);

    if (u + 1 < u1) {
      stage(u + 1, cb ^ 1);                       // prefetch next unit
      asm volatile("s_waitcnt vmcnt(4)" ::: "memory");  // wait only for current
    } else {
      asm volatile("s_waitcnt vmcnt(0)" ::: "memory");
    }
    __builtin_amdgcn_s_barrier();
    asm volatile("" ::: "memory");

    if (kv0 <= qw + 15) {
      // ---- QK^T (swapped): S^T[kv][q] ----
      f32x4 st[2] = {};
      __builtin_amdgcn_s_setprio(1);
#pragma unroll
      for (int tt = 0; tt < 2; ++tt) {
        const int krow = (tt << 4) + c;
        const char* kbase = Kl + krow * 256;
        const int swk = (krow & 7) << 4;
#pragma unroll
        for (int kc = 0; kc < 4; ++kc) {
          short8 kf = *(const short8*)(kbase + ((kc * 64 + g * 16) ^ swk));
          st[tt] = __builtin_amdgcn_mfma_f32_16x16x32_bf16(kf, qf[kc], st[tt], 0, 0, 0);
        }
      }
      __builtin_amdgcn_s_setprio(0);
      // ---- causal mask ----
#pragma unroll
      for (int tt = 0; tt < 2; ++tt) {
        if (kv0 + (tt << 4) + 15 > qw) {
          const int kvb = kv0 + (tt << 4) + (g << 2);
#pragma unroll
          for (int r = 0; r < 4; ++r)
            if (kvb + r > qw + c) st[tt][r] = -__builtin_inff();
        }
      }
      // ---- online softmax (exp2 domain), per-lane q = c ----
      float mx = fmaxf(fmaxf(fmaxf(st[0][0], st[0][1]), fmaxf(st[0][2], st[0][3])),
                       fmaxf(fmaxf(st[1][0], st[1][1]), fmaxf(st[1][2], st[1][3])));
      mx = fmaxf(mx, __shfl_xor(mx, 16));
      mx = fmaxf(mx, __shfl_xor(mx, 32));
      const float m2new = fmaxf(m2, mx);
      const float alpha = exp2f(m2 - m2new);
      float p[8], psum = 0.f;
#pragma unroll
      for (int tt = 0; tt < 2; ++tt)
#pragma unroll
        for (int r = 0; r < 4; ++r) {
          const float v = exp2f(st[tt][r] - m2new);
          p[(tt << 2) + r] = v;
          psum += v;
        }
      psum += __shfl_xor(psum, 16);
      psum += __shfl_xor(psum, 32);
      lsum = lsum * alpha + psum;
      m2 = m2new;
#pragma unroll
      for (int r = 0; r < 4; ++r) {
        const float fr = __shfl(alpha, (g << 2) + r);
#pragma unroll
        for (int d = 0; d < 8; ++d) acc[d][r] *= fr;
      }
      // ---- P -> bf16 per-wave LDS ----
      {
        char* prow = Pl + c * 64;
#pragma unroll
        for (int tt = 0; tt < 2; ++tt)
#pragma unroll
          for (int uu = 0; uu < 2; ++uu)
            *(unsigned int*)(prow + ((((tt << 5) + (g << 3) + (uu << 2))) ^ swp)) =
                pk2(p[(tt << 2) + (uu << 1)], p[(tt << 2) + (uu << 1) + 1]);
      }
      // ---- PV ----
      {
        const short8 pa = *(const short8*)(Pl + c * 64 + ((g << 4) ^ swp));
        __builtin_amdgcn_s_setprio(1);
#pragma unroll
        for (int d = 0; d < 8; ++d) {
          const short8 vb = *(const short8*)(Vl + (d << 10) + c * 64 + ((g << 4) ^ swp));
          acc[d] = __builtin_amdgcn_mfma_f32_16x16x32_bf16(pa, vb, acc[d], 0, 0, 0);
        }
        __builtin_amdgcn_s_setprio(0);
      }
    }
    asm volatile("" ::: "memory");
    __builtin_amdgcn_s_barrier();
  }

  // ---- epilogue: partial O and (m, l) ----
  float* op = Opart + (size_t)slot * 8192 + (size_t)(w << 4) * 128;
#pragma unroll
  for (int d = 0; d < 8; ++d)
#pragma unroll
    for (int r = 0; r < 4; ++r)
      op[((g << 2) + r) * 128 + (d << 4) + c] = acc[d][r];
  if (lane < 16)
    MLpart[slot * 64 + (w << 4) + lane] = make_float2(m2, lsum);
}

// ---------- combine variable-count partials ----------
__global__ void combine_kernel(const float* __restrict__ Opart,
                               const float2* __restrict__ MLpart,
                               float* __restrict__ Out, int U) {
  const int gidx = blockIdx.x * 256 + threadIdx.x;  // 8192*32
  const int q = gidx >> 5;
  const int cb = (gidx & 31) << 2;
  const int t = q >> 6, rl = q & 63;
  const int ns = (nunits(t) + U - 1) / U;
  int base = 0;
  for (int tt = NT - 1; tt > t; --tt) base += (nunits(tt) + U - 1) / U;

  float M = -3e38f;
  for (int s2 = 0; s2 < ns; ++s2)
    M = fmaxf(M, MLpart[(base + s2) * 64 + rl].x);
  float nx = 0, ny = 0, nz = 0, nw = 0, den = 0;
  for (int s2 = 0; s2 < ns; ++s2) {
    const float2 ml = MLpart[(base + s2) * 64 + rl];
    if (ml.x > -1e37f) {
      const float wg = exp2f(ml.x - M);
      den += ml.y * wg;
      const float4 o = *(const float4*)(Opart + (size_t)(base + s2) * 8192 + rl * 128 + cb);
      nx += wg * o.x; ny += wg * o.y; nz += wg * o.z; nw += wg * o.w;
    }
  }
  const float inv = 1.f / den;
  float4 r; r.x = nx * inv; r.y = ny * inv; r.z = nz * inv; r.w = nw * inv;
  *(float4*)(Out + (size_t)q * 128 + cb) = r;
}

extern "C" void kernel_launch(void* const* d_in, const int* in_sizes, int n_in,
                              void* d_out, int out_size, void* d_ws, size_t ws_size,
                              hipStream_t stream) {
  (void)in_sizes; (void)n_in; (void)out_size;
  const float* Q = (const float*)d_in[0];
  const float* K = (const float*)d_in[1];
  const float* V = (const float*)d_in[2];
  float* out = (float*)d_out;
  char* ws = (char*)d_ws;

  // pick U (units per block) so partials fit in ws
  int U = 16;
  long slots = 0;
  for (;;) {
    slots = 0;
    for (int t = 0; t < NT; ++t) slots += (nunits(t) + U - 1) / U;
    size_t need = (size_t)(8u << 20) + (size_t)slots * 64 * 128 * 4;
    if (need <= ws_size || U >= 256) break;
    U <<= 1;
  }

  unsigned short* Qb  = (unsigned short*)(ws);
  unsigned short* Kb  = (unsigned short*)(ws + (1u << 21));
  unsigned short* Vtb = (unsigned short*)(ws + (2u << 21));
  float2* MLp = (float2*)(ws + (3u << 21));          // <= 2MB for slots<=4096
  float*  Op  = (float*)(ws + (8u << 20));

  const float qscale = 0.12751742941349835f;  // (1/sqrt(128)) * log2(e)
  cast_kernel<<<512, 256, 0, stream>>>(Q, Qb, 131072, qscale);
  cast_kernel<<<512, 256, 0, stream>>>(K, Kb, 131072, 1.0f);
  transpose_v_kernel<<<256, 256, 0, stream>>>(V, Vtb);
  attn_kernel<<<(int)slots, 256, 0, stream>>>(Qb, Kb, Vtb, Op, MLp, U);
  combine_kernel<<<1024, 256, 0, stream>>>(Op, MLp, out, U);
}

// Round 4
// 80.826 us; speedup vs baseline: 1.3239x; 1.2009x over previous
//
#include <hip/hip_runtime.h>
#include <stdint.h>

typedef __attribute__((ext_vector_type(8))) short short8;
typedef __attribute__((ext_vector_type(4))) float f32x4;

#define D_K 128
#define N_KV 8192
#define NT 128          /* 64-row q tiles */

// ---------- helpers ----------
__device__ __forceinline__ unsigned short f2bf(float x) {
  unsigned int u = __float_as_uint(x);
  u += 0x7FFFu + ((u >> 16) & 1u);  // RNE
  return (unsigned short)(u >> 16);
}
__device__ __forceinline__ unsigned int pk2(float lo, float hi) {
  return (unsigned int)f2bf(lo) | ((unsigned int)f2bf(hi) << 16);
}
__device__ __forceinline__ void gload16(const void* g, void* l) {
  __builtin_amdgcn_global_load_lds(
      (const __attribute__((address_space(1))) unsigned int*)g,
      (__attribute__((address_space(3))) unsigned int*)l, 16, 0, 0);
}
__device__ __host__ __forceinline__ int nunits(int t) {
  int n = 2 * t + 2;
  return n > 252 ? 252 : n;
}

// ---------- fused prep: Q-cast, K-cast, V-transpose in one launch ----------
__global__ void prep_kernel(const float* __restrict__ Q,
                            const float* __restrict__ K,
                            const float* __restrict__ V,
                            unsigned short* __restrict__ Qb,
                            unsigned short* __restrict__ Kb,
                            unsigned short* __restrict__ Vtb) {
  __shared__ unsigned short tile[64][65];
  const int b = blockIdx.x;
  const int tid = threadIdx.x;
  if (b < 1024) {
    const float scale = (b < 512) ? 0.12751742941349835f : 1.0f;  // (1/sqrt(128))*log2(e)
    const float* src = (b < 512) ? Q : K;
    unsigned short* dst = (b < 512) ? Qb : Kb;
    const int i = (b & 511) * 256 + tid;
    const float4* s = (const float4*)src;
    float4 a = s[2 * i], c4 = s[2 * i + 1];
    uint4 o;
    o.x = pk2(a.x * scale, a.y * scale);
    o.y = pk2(a.z * scale, a.w * scale);
    o.z = pk2(c4.x * scale, c4.y * scale);
    o.w = pk2(c4.z * scale, c4.w * scale);
    *(uint4*)(dst + (size_t)i * 8) = o;
  } else {
    const int bb = b - 1024;
    const int kv0 = (bb >> 1) << 6, dk0 = (bb & 1) << 6;
    const int r = tid >> 2;
    const int c0 = (tid & 3) << 4;
#pragma unroll
    for (int j = 0; j < 4; ++j) {
      float4 v = *(const float4*)(V + (size_t)(kv0 + r) * D_K + dk0 + c0 + 4 * j);
      tile[r][c0 + 4 * j + 0] = f2bf(v.x);
      tile[r][c0 + 4 * j + 1] = f2bf(v.y);
      tile[r][c0 + 4 * j + 2] = f2bf(v.z);
      tile[r][c0 + 4 * j + 3] = f2bf(v.w);
    }
    __syncthreads();
    __align__(16) unsigned short tmp[16];
#pragma unroll
    for (int j = 0; j < 16; ++j) tmp[j] = tile[c0 + j][r];
    unsigned short* o = Vtb + (size_t)(dk0 + r) * N_KV + kv0 + c0;
    *(uint4*)(o) = *(uint4*)(tmp);
    *(uint4*)(o + 8) = *(uint4*)(tmp + 8);
  }
}

// ---------- main: 3-buffer 1-barrier pipelined flash attention ----------
__global__ __launch_bounds__(256, 3) void attn_kernel(
    const unsigned short* __restrict__ Qb,   // [8192][128] bf16 pre-scaled
    const unsigned short* __restrict__ Kb,   // [8192][128] bf16
    const unsigned short* __restrict__ Vtb,  // [128][8192] bf16
    float* __restrict__ Opart,               // [slots][64][128]
    float2* __restrict__ MLpart,             // [slots][64]
    int U) {
  // ---- block -> (tile t, chunk s); big tiles first ----
  int rem = blockIdx.x, t = NT - 1;
  for (;; --t) {
    int nb = (nunits(t) + U - 1) / U;
    if (rem < nb) break;
    rem -= nb;
  }
  const int s = rem;
  const int q0 = t << 6;
  const int n = nunits(t);
  const int u0 = s * U;
  const int u1 = min(u0 + U, n);
  const int slot = blockIdx.x;
  const int tid = threadIdx.x;
  const int lane = tid & 63;
  const int w = tid >> 6;
  const int c = lane & 15;
  const int g = lane >> 4;
  const int qw = q0 + (w << 4);

  __shared__ __align__(16) char lds[49152];  // 3 x (K 8KB + Vt 8KB)

  // Q fragments (B operand): lane(c,g) = Q[qw+c][kc*32 + 8g .. +7]
  short8 qf[4];
  {
    const char* qrow = (const char*)(Qb + (size_t)(qw + c) * D_K);
#pragma unroll
    for (int kc = 0; kc < 4; ++kc)
      qf[kc] = *(const short8*)(qrow + kc * 64 + g * 16);
  }

  f32x4 acc[8] = {};
  float m2 = -3e38f, lsum = 0.f;
  const int swp = (c & 3) << 4;

  // staging constants (pre-swizzled source, linear LDS dest)
  int kcst[2], vcst[2], ldk[2], ldv[2];
#pragma unroll
  for (int ii = 0; ii < 2; ++ii) {
    const int ck = 2 * w + ii;
    const int rowK = (ck << 2) + (lane >> 4);
    kcst[ii] = rowK * 256 + (((lane & 15) << 4) ^ ((rowK & 7) << 4));
    ldk[ii] = ck << 10;
    const int rowV = (ck << 4) + (lane >> 2);
    vcst[ii] = rowV * 16384 + (((lane & 3) << 4) ^ ((rowV & 3) << 4));
    ldv[ii] = 8192 + (ck << 10);
  }
  auto stage = [&](int u, int b) {
    char* base = lds + b * 16384;
    const int koff = (u << 5) * 256;
    const int voff = (u << 5) * 2;
#pragma unroll
    for (int ii = 0; ii < 2; ++ii) {
      gload16((const char*)Kb + koff + kcst[ii], base + ldk[ii]);
      gload16((const char*)Vtb + voff + vcst[ii], base + ldv[ii]);
    }
  };

  stage(u0, 0);
  if (u0 + 1 < u1) stage(u0 + 1, 1);
  int cb = 0;
  for (int u = u0; u < u1; ++u) {
    if (u + 1 < u1) asm volatile("s_waitcnt vmcnt(4)" ::: "memory");
    else            asm volatile("s_waitcnt vmcnt(0)" ::: "memory");
    __builtin_amdgcn_s_barrier();
    asm volatile("" ::: "memory");
    if (u + 2 < u1) {
      int nb2 = cb + 2; if (nb2 >= 3) nb2 -= 3;
      stage(u + 2, nb2);
    }
    const int kv0 = u << 5;
    char* const Kl = lds + cb * 16384;
    char* const Vl = Kl + 8192;

    if (kv0 <= qw + 15) {
      // ---- QK^T (swapped): st[tt][r] = S^T[kv=16tt+4g+r][q=c] ----
      f32x4 st[2] = {};
      __builtin_amdgcn_s_setprio(1);
#pragma unroll
      for (int tt = 0; tt < 2; ++tt) {
        const int krow = (tt << 4) + c;
        const char* kbase = Kl + krow * 256;
        const int swk = (krow & 7) << 4;
#pragma unroll
        for (int kc = 0; kc < 4; ++kc) {
          short8 kf = *(const short8*)(kbase + ((kc * 64 + g * 16) ^ swk));
          st[tt] = __builtin_amdgcn_mfma_f32_16x16x32_bf16(kf, qf[kc], st[tt], 0, 0, 0);
        }
      }
      __builtin_amdgcn_s_setprio(0);
      // ---- causal mask ----
#pragma unroll
      for (int tt = 0; tt < 2; ++tt) {
        if (kv0 + (tt << 4) + 15 > qw) {
          const int kvb = kv0 + (tt << 4) + (g << 2);
#pragma unroll
          for (int r = 0; r < 4; ++r)
            if (kvb + r > qw + c) st[tt][r] = -__builtin_inff();
        }
      }
      // ---- online softmax (exp2 domain), per-lane q = c, defer-max ----
      float mx = fmaxf(fmaxf(fmaxf(st[0][0], st[0][1]), fmaxf(st[0][2], st[0][3])),
                       fmaxf(fmaxf(st[1][0], st[1][1]), fmaxf(st[1][2], st[1][3])));
      mx = fmaxf(mx, __shfl_xor(mx, 16));
      mx = fmaxf(mx, __shfl_xor(mx, 32));
      if (!__all(mx <= m2 + 8.0f)) {             // T13: rescale only when needed
        const float m2new = fmaxf(m2, mx);
        const float alpha = exp2f(m2 - m2new);
        lsum *= alpha;
#pragma unroll
        for (int r = 0; r < 4; ++r) {
          const float fr = __shfl(alpha, (g << 2) + r);
#pragma unroll
          for (int d = 0; d < 8; ++d) acc[d][r] *= fr;
        }
        m2 = m2new;
      }
      float p[8], psum = 0.f;
#pragma unroll
      for (int tt = 0; tt < 2; ++tt)
#pragma unroll
        for (int r = 0; r < 4; ++r) {
          const float v = exp2f(st[tt][r] - m2);
          p[(tt << 2) + r] = v;
          psum += v;
        }
      psum += __shfl_xor(psum, 16);
      psum += __shfl_xor(psum, 32);
      lsum += psum;
      // ---- P redistribution in-register: C-row layout -> A k-layout ----
      // dest (c,g) word m <- source lane c+32(g&1)+16(m>>1), word 2(g>>1)+(m&1).
      // shfl evaluates operand on SOURCE lane, so shuffle both tt-halves and
      // select with the DESTINATION's hi=(g>>1).  (R3 bug: selected with source's.)
      unsigned int wv0 = pk2(p[0], p[1]), wv1 = pk2(p[2], p[3]);
      unsigned int wv2 = pk2(p[4], p[5]), wv3 = pk2(p[6], p[7]);
      const bool hi = (g >> 1) != 0;
      const int srcb = c + ((g & 1) << 5);
      union { unsigned int u4[4]; short8 s8; } pu;
      {
        const unsigned int a0 = (unsigned int)__shfl((int)wv0, srcb);
        const unsigned int b0 = (unsigned int)__shfl((int)wv2, srcb);
        const unsigned int a1 = (unsigned int)__shfl((int)wv1, srcb);
        const unsigned int b1 = (unsigned int)__shfl((int)wv3, srcb);
        const unsigned int a2 = (unsigned int)__shfl((int)wv0, srcb + 16);
        const unsigned int b2 = (unsigned int)__shfl((int)wv2, srcb + 16);
        const unsigned int a3 = (unsigned int)__shfl((int)wv1, srcb + 16);
        const unsigned int b3 = (unsigned int)__shfl((int)wv3, srcb + 16);
        pu.u4[0] = hi ? b0 : a0;
        pu.u4[1] = hi ? b1 : a1;
        pu.u4[2] = hi ? b2 : a2;
        pu.u4[3] = hi ? b3 : a3;
      }
      const short8 pa = pu.s8;                   // P[q=c][kv=8g..8g+7]
      // ---- PV ----
      __builtin_amdgcn_s_setprio(1);
#pragma unroll
      for (int d = 0; d < 8; ++d) {
        const short8 vb = *(const short8*)(Vl + (d << 10) + c * 64 + ((g << 4) ^ swp));
        acc[d] = __builtin_amdgcn_mfma_f32_16x16x32_bf16(pa, vb, acc[d], 0, 0, 0);
      }
      __builtin_amdgcn_s_setprio(0);
    }
    if (++cb == 3) cb = 0;
  }

  // ---- epilogue: partial O and (m, l) ----
  float* op = Opart + (size_t)slot * 8192 + (size_t)(w << 4) * 128;
#pragma unroll
  for (int d = 0; d < 8; ++d)
#pragma unroll
    for (int r = 0; r < 4; ++r)
      op[((g << 2) + r) * 128 + (d << 4) + c] = acc[d][r];
  if (lane < 16)
    MLpart[slot * 64 + (w << 4) + lane] = make_float2(m2, lsum);
}

// ---------- combine variable-count partials ----------
__global__ void combine_kernel(const float* __restrict__ Opart,
                               const float2* __restrict__ MLpart,
                               float* __restrict__ Out, int U) {
  const int gidx = blockIdx.x * 256 + threadIdx.x;  // 8192*32
  const int q = gidx >> 5;
  const int cb = (gidx & 31) << 2;
  const int t = q >> 6, rl = q & 63;
  const int ns = (nunits(t) + U - 1) / U;
  int base = 0;
  for (int tt = NT - 1; tt > t; --tt) base += (nunits(tt) + U - 1) / U;

  float M = -3e38f;
  for (int s2 = 0; s2 < ns; ++s2)
    M = fmaxf(M, MLpart[(base + s2) * 64 + rl].x);
  float nx = 0, ny = 0, nz = 0, nw = 0, den = 0;
  for (int s2 = 0; s2 < ns; ++s2) {
    const float2 ml = MLpart[(base + s2) * 64 + rl];
    if (ml.x > -1e37f) {
      const float wg = exp2f(ml.x - M);
      den += ml.y * wg;
      const float4 o = *(const float4*)(Opart + (size_t)(base + s2) * 8192 + rl * 128 + cb);
      nx += wg * o.x; ny += wg * o.y; nz += wg * o.z; nw += wg * o.w;
    }
  }
  const float inv = 1.f / den;
  float4 r; r.x = nx * inv; r.y = ny * inv; r.z = nz * inv; r.w = nw * inv;
  *(float4*)(Out + (size_t)q * 128 + cb) = r;
}

extern "C" void kernel_launch(void* const* d_in, const int* in_sizes, int n_in,
                              void* d_out, int out_size, void* d_ws, size_t ws_size,
                              hipStream_t stream) {
  (void)in_sizes; (void)n_in; (void)out_size;
  const float* Q = (const float*)d_in[0];
  const float* K = (const float*)d_in[1];
  const float* V = (const float*)d_in[2];
  float* out = (float*)d_out;
  char* ws = (char*)d_ws;

  // pick U so slots <= 768 (one residency pass at 3 blocks/CU) and ws fits
  int U = 2;
  long slots = 0;
  for (;;) {
    slots = 0;
    for (int t = 0; t < NT; ++t) slots += (nunits(t) + U - 1) / U;
    size_t need = (size_t)(8u << 20) + (size_t)slots * 64 * 128 * 4;
    if ((slots <= 768 && need <= ws_size) || U >= 252) break;
    ++U;
  }

  unsigned short* Qb  = (unsigned short*)(ws);
  unsigned short* Kb  = (unsigned short*)(ws + (1u << 21));
  unsigned short* Vtb = (unsigned short*)(ws + (2u << 21));
  float2* MLp = (float2*)(ws + (3u << 21));
  float*  Op  = (float*)(ws + (8u << 20));

  prep_kernel<<<1280, 256, 0, stream>>>(Q, K, V, Qb, Kb, Vtb);
  attn_kernel<<<(int)slots, 256, 0, stream>>>(Qb, Kb, Vtb, Op, MLp, U);
  combine_kernel<<<1024, 256, 0, stream>>>(Op, MLp, out, U);
}